// Round 9
// baseline (298.876 us; speedup 1.0000x reference)
//
#include <hip/hip_runtime.h>

// softmax(relu(nv1 @ nv2), axis=1)
// nv1: [8192, 10] f32, nv2: [10, 8192] f32, out: [8192, 8192] f32
//
// Round 9 = round 8 resubmitted (r8 bench hit GPUAcquisitionTimeout, no data):
// round-7 structure + NONTEMPORAL stores in k2 (the one lever untested on the
// fill-shaped kernel; r5's NT test was confounded by the 1-block/CU shape).
// Theory: k2 stores (3.9 TB/s effective) are throttled by L2 dirty-writeback
// against the just-poisoned out region; `nt` streams full lines past L2.
//   k1: rowsum[r] = sum_j exp(relu(nv1[r,:] . nv2[:,j]))  (raw sum to d_ws)
//   k2: out[r,j]  = exp2(fmax(acc,0) - log2(rowsum[r])), acc pre-scaled l2e

#define NODES 8192
#define RANK  10
#define L2E   1.4426950408889634f

typedef float f32x4 __attribute__((ext_vector_type(4)));

// ---------------- kernel 1: row sums (TPB=1024, full row per block) --------
#define K1_TPB   1024
#define K1_NWAVE (K1_TPB / 64)        // 16
#define K1_RPB   32                   // rows per block
#define K1_NBLK  (NODES / K1_RPB)     // 256
#define K1_CHUNK 8

__global__ __launch_bounds__(K1_TPB)
void rowsum_kernel(const float* __restrict__ nv1,
                   const float* __restrict__ nv2,
                   float* __restrict__ rowsum)
{
    const int t    = threadIdx.x;
    const int lane = t & 63;
    const int wave = t >> 6;
    const int row0 = blockIdx.x * K1_RPB;

    // This thread's 8 nv2 columns, register-resident, pre-scaled by log2(e).
    float4 b[2][RANK];
#pragma unroll
    for (int g = 0; g < 2; ++g) {
        const int j = g * 4096 + t * 4;
#pragma unroll
        for (int k = 0; k < RANK; ++k) {
            float4 v = *reinterpret_cast<const float4*>(nv2 + k * NODES + j);
            v.x *= L2E; v.y *= L2E; v.z *= L2E; v.w *= L2E;
            b[g][k] = v;
        }
    }

    __shared__ float red[K1_NWAVE][K1_RPB];

    for (int c = 0; c < K1_RPB; c += K1_CHUNK) {
        float psum[K1_CHUNK];
#pragma unroll
        for (int r = 0; r < K1_CHUNK; ++r) {
            const int row = row0 + c + r;            // uniform -> scalar loads
            float a[RANK];
#pragma unroll
            for (int k = 0; k < RANK; ++k) a[k] = nv1[row * RANK + k];

            float sum = 0.0f;
#pragma unroll
            for (int g = 0; g < 2; ++g) {
                float4 acc = make_float4(0.f, 0.f, 0.f, 0.f);
#pragma unroll
                for (int k = 0; k < RANK; ++k) {
                    acc.x = fmaf(a[k], b[g][k].x, acc.x);
                    acc.y = fmaf(a[k], b[g][k].y, acc.y);
                    acc.z = fmaf(a[k], b[g][k].z, acc.z);
                    acc.w = fmaf(a[k], b[g][k].w, acc.w);
                }
                sum += __builtin_amdgcn_exp2f(fmaxf(acc.x, 0.f))
                     + __builtin_amdgcn_exp2f(fmaxf(acc.y, 0.f))
                     + __builtin_amdgcn_exp2f(fmaxf(acc.z, 0.f))
                     + __builtin_amdgcn_exp2f(fmaxf(acc.w, 0.f));
            }
            psum[r] = sum;
        }
#pragma unroll
        for (int r = 0; r < K1_CHUNK; ++r) {
#pragma unroll
            for (int m = 32; m >= 1; m >>= 1)
                psum[r] += __shfl_xor(psum[r], m, 64);
        }
        if (lane == 0) {
#pragma unroll
            for (int r = 0; r < K1_CHUNK; ++r) red[wave][c + r] = psum[r];
        }
    }

    __syncthreads();                 // the ONLY barrier
    if (t < K1_RPB) {
        float s = 0.0f;
#pragma unroll
        for (int w = 0; w < K1_NWAVE; ++w) s += red[w][t];
        rowsum[row0 + t] = s;        // raw sum; k2 folds 1/s into the exponent
    }
}

// ---------------- kernel 2: resident streamer, NT stores -------------------
#define K2_TPB   256
#define K2_RPB   8
#define K2_SEGW  (K2_TPB * 4)            // 1024 columns per segment
#define K2_NSEG  (NODES / K2_SEGW)       // 8
#define K2_GRID  2048
#define K2_RSTR  (K2_GRID / K2_NSEG)     // 256 row-block stride
#define K2_ITERS (NODES / K2_RPB / K2_RSTR)   // 4

__global__ __launch_bounds__(K2_TPB, 8)
void stream_kernel(const float* __restrict__ nv1,
                   const float* __restrict__ nv2,
                   const float* __restrict__ rowsum,
                   float* __restrict__ out)
{
    const int t     = threadIdx.x;
    const int seg   = blockIdx.x & (K2_NSEG - 1);
    const int rbase = blockIdx.x >> 3;            // 0..255
    const int j     = seg * K2_SEGW + t * 4;

    // nv2 slice pre-scaled by log2(e): 40 VGPRs, loaded once per block.
    float4 b[RANK];
#pragma unroll
    for (int k = 0; k < RANK; ++k) {
        float4 v = *reinterpret_cast<const float4*>(nv2 + k * NODES + j);
        v.x *= L2E; v.y *= L2E; v.z *= L2E; v.w *= L2E;
        b[k] = v;
    }

    for (int i = 0; i < K2_ITERS; ++i) {
        const int row0 = (rbase + i * K2_RSTR) * K2_RPB;
#pragma unroll 2
        for (int r = 0; r < K2_RPB; ++r) {
            const int row = row0 + r;                 // uniform
            const float nc = -__builtin_amdgcn_logf(rowsum[row]); // -log2(sum)
            float a[RANK];
#pragma unroll
            for (int k = 0; k < RANK; ++k) a[k] = nv1[row * RANK + k];

            float4 acc = make_float4(0.f, 0.f, 0.f, 0.f);
#pragma unroll
            for (int k = 0; k < RANK; ++k) {
                acc.x = fmaf(a[k], b[k].x, acc.x);
                acc.y = fmaf(a[k], b[k].y, acc.y);
                acc.z = fmaf(a[k], b[k].z, acc.z);
                acc.w = fmaf(a[k], b[k].w, acc.w);
            }
            f32x4 o;
            o.x = __builtin_amdgcn_exp2f(fmaxf(acc.x, 0.f) + nc);
            o.y = __builtin_amdgcn_exp2f(fmaxf(acc.y, 0.f) + nc);
            o.z = __builtin_amdgcn_exp2f(fmaxf(acc.z, 0.f) + nc);
            o.w = __builtin_amdgcn_exp2f(fmaxf(acc.w, 0.f) + nc);
            __builtin_nontemporal_store(
                o, reinterpret_cast<f32x4*>(out + (size_t)row * NODES + j));
        }
    }
}

extern "C" void kernel_launch(void* const* d_in, const int* in_sizes, int n_in,
                              void* d_out, int out_size, void* d_ws, size_t ws_size,
                              hipStream_t stream)
{
    const float* nv1 = (const float*)d_in[0];   // [8192, 10]
    const float* nv2 = (const float*)d_in[1];   // [10, 8192]
    float* out    = (float*)d_out;              // [8192, 8192]
    float* rowsum = (float*)d_ws;               // 8192 floats of scratch

    rowsum_kernel<<<K1_NBLK, K1_TPB, 0, stream>>>(nv1, nv2, rowsum);
    stream_kernel<<<K2_GRID, K2_TPB, 0, stream>>>(nv1, nv2, rowsum, out);
}

// Round 10
// 289.516 us; speedup vs baseline: 1.0323x; 1.0323x over previous
//
#include <hip/hip_runtime.h>

// softmax(relu(nv1 @ nv2), axis=1)
// nv1: [8192, 10] f32, nv2: [10, 8192] f32, out: [8192, 8192] f32
//
// Round 10 = round 7 exactly (plain float4 stores). NT stores measured
// HARMFUL on gfx950 (r5: 299.9, r9: 298.9 vs plain r6: 288.1, r7: 289.9) —
// the nt bit defeats L2 write-combining on this path. Reverting to the
// best-measured configuration.
//
// Final structure & accounting (stable over r6-r9):
//   dur_us ~= 206 us harness poison-fills (fixed) + k1 ~13 us + k2 ~69 us.
//   k1 is at its VALU floor (67M x (10 FMA + exp) ~= 14 us).
//   k2: 268 MB output write, 42 us pure-write floor; occupancy reshape was
//   the only lever that moved it (-12 us). Barriers, nv2 reloads, exp diet,
//   NT stores: all neutral or harmful.

#define NODES 8192
#define RANK  10
#define L2E   1.4426950408889634f

// ---------------- kernel 1: row sums (TPB=1024, full row per block) --------
#define K1_TPB   1024
#define K1_NWAVE (K1_TPB / 64)        // 16
#define K1_RPB   32                   // rows per block
#define K1_NBLK  (NODES / K1_RPB)     // 256
#define K1_CHUNK 8

__global__ __launch_bounds__(K1_TPB)
void rowsum_kernel(const float* __restrict__ nv1,
                   const float* __restrict__ nv2,
                   float* __restrict__ rowsum)
{
    const int t    = threadIdx.x;
    const int lane = t & 63;
    const int wave = t >> 6;
    const int row0 = blockIdx.x * K1_RPB;

    // This thread's 8 nv2 columns, register-resident, pre-scaled by log2(e).
    float4 b[2][RANK];
#pragma unroll
    for (int g = 0; g < 2; ++g) {
        const int j = g * 4096 + t * 4;
#pragma unroll
        for (int k = 0; k < RANK; ++k) {
            float4 v = *reinterpret_cast<const float4*>(nv2 + k * NODES + j);
            v.x *= L2E; v.y *= L2E; v.z *= L2E; v.w *= L2E;
            b[g][k] = v;
        }
    }

    __shared__ float red[K1_NWAVE][K1_RPB];

    for (int c = 0; c < K1_RPB; c += K1_CHUNK) {
        float psum[K1_CHUNK];
#pragma unroll
        for (int r = 0; r < K1_CHUNK; ++r) {
            const int row = row0 + c + r;            // uniform -> scalar loads
            float a[RANK];
#pragma unroll
            for (int k = 0; k < RANK; ++k) a[k] = nv1[row * RANK + k];

            float sum = 0.0f;
#pragma unroll
            for (int g = 0; g < 2; ++g) {
                float4 acc = make_float4(0.f, 0.f, 0.f, 0.f);
#pragma unroll
                for (int k = 0; k < RANK; ++k) {
                    acc.x = fmaf(a[k], b[g][k].x, acc.x);
                    acc.y = fmaf(a[k], b[g][k].y, acc.y);
                    acc.z = fmaf(a[k], b[g][k].z, acc.z);
                    acc.w = fmaf(a[k], b[g][k].w, acc.w);
                }
                // acc is (a.b)*log2(e); exp2(relu(acc)) == exp(relu(a.b))
                sum += __builtin_amdgcn_exp2f(fmaxf(acc.x, 0.f))
                     + __builtin_amdgcn_exp2f(fmaxf(acc.y, 0.f))
                     + __builtin_amdgcn_exp2f(fmaxf(acc.z, 0.f))
                     + __builtin_amdgcn_exp2f(fmaxf(acc.w, 0.f));
            }
            psum[r] = sum;
        }
#pragma unroll
        for (int r = 0; r < K1_CHUNK; ++r) {
#pragma unroll
            for (int m = 32; m >= 1; m >>= 1)
                psum[r] += __shfl_xor(psum[r], m, 64);
        }
        if (lane == 0) {
#pragma unroll
            for (int r = 0; r < K1_CHUNK; ++r) red[wave][c + r] = psum[r];
        }
    }

    __syncthreads();                 // the ONLY barrier
    if (t < K1_RPB) {
        float s = 0.0f;
#pragma unroll
        for (int w = 0; w < K1_NWAVE; ++w) s += red[w][t];
        rowsum[row0 + t] = s;        // raw sum; k2 folds 1/s into the exponent
    }
}

// ---------------- kernel 2: resident streamer ------------------------------
// 2048 blocks = 8/CU, all co-resident. Block pins column segment, loads nv2
// slice once, strides 4 row-blocks x 8 rows. Plain float4 stores.
#define K2_TPB   256
#define K2_RPB   8
#define K2_SEGW  (K2_TPB * 4)            // 1024 columns per segment
#define K2_NSEG  (NODES / K2_SEGW)       // 8
#define K2_GRID  2048
#define K2_RSTR  (K2_GRID / K2_NSEG)     // 256 row-block stride
#define K2_ITERS (NODES / K2_RPB / K2_RSTR)   // 4

__global__ __launch_bounds__(K2_TPB, 8)
void stream_kernel(const float* __restrict__ nv1,
                   const float* __restrict__ nv2,
                   const float* __restrict__ rowsum,
                   float* __restrict__ out)
{
    const int t     = threadIdx.x;
    const int seg   = blockIdx.x & (K2_NSEG - 1);
    const int rbase = blockIdx.x >> 3;            // 0..255
    const int j     = seg * K2_SEGW + t * 4;

    // nv2 slice pre-scaled by log2(e): 40 VGPRs, loaded once per block.
    float4 b[RANK];
#pragma unroll
    for (int k = 0; k < RANK; ++k) {
        float4 v = *reinterpret_cast<const float4*>(nv2 + k * NODES + j);
        v.x *= L2E; v.y *= L2E; v.z *= L2E; v.w *= L2E;
        b[k] = v;
    }

    for (int i = 0; i < K2_ITERS; ++i) {
        const int row0 = (rbase + i * K2_RSTR) * K2_RPB;
#pragma unroll 2
        for (int r = 0; r < K2_RPB; ++r) {
            const int row = row0 + r;                 // uniform
            const float nc = -__builtin_amdgcn_logf(rowsum[row]); // -log2(sum)
            float a[RANK];
#pragma unroll
            for (int k = 0; k < RANK; ++k) a[k] = nv1[row * RANK + k];

            float4 acc = make_float4(0.f, 0.f, 0.f, 0.f);
#pragma unroll
            for (int k = 0; k < RANK; ++k) {
                acc.x = fmaf(a[k], b[k].x, acc.x);
                acc.y = fmaf(a[k], b[k].y, acc.y);
                acc.z = fmaf(a[k], b[k].z, acc.z);
                acc.w = fmaf(a[k], b[k].w, acc.w);
            }
            float4 o;
            o.x = __builtin_amdgcn_exp2f(fmaxf(acc.x, 0.f) + nc);
            o.y = __builtin_amdgcn_exp2f(fmaxf(acc.y, 0.f) + nc);
            o.z = __builtin_amdgcn_exp2f(fmaxf(acc.z, 0.f) + nc);
            o.w = __builtin_amdgcn_exp2f(fmaxf(acc.w, 0.f) + nc);
            *reinterpret_cast<float4*>(out + (size_t)row * NODES + j) = o;
        }
    }
}

extern "C" void kernel_launch(void* const* d_in, const int* in_sizes, int n_in,
                              void* d_out, int out_size, void* d_ws, size_t ws_size,
                              hipStream_t stream)
{
    const float* nv1 = (const float*)d_in[0];   // [8192, 10]
    const float* nv2 = (const float*)d_in[1];   // [10, 8192]
    float* out    = (float*)d_out;              // [8192, 8192]
    float* rowsum = (float*)d_ws;               // 8192 floats of scratch

    rowsum_kernel<<<K1_NBLK, K1_TPB, 0, stream>>>(nv1, nv2, rowsum);
    stream_kernel<<<K2_GRID, K2_TPB, 0, stream>>>(nv1, nv2, rowsum, out);
}